// Round 13
// baseline (87.833 us; speedup 1.0000x reference)
//
#include <hip/hip_runtime.h>

// Problem constants (from reference)
#define B_    64
#define T_    256
#define VG_   1232
#define S_    32
#define LW_   64
#define VW_   8000
#define NTAGS 8
#define NEG_  (-1e30f)
#define LP_STRIDE 34   // per (b,t): [0]=blank lp, [1..32]=gloss lp, [33]=pad
#define LOG2E 1.44269504088896340736f
#define LN2   0.69314718055994530942f

__device__ __forceinline__ float exp2g(float x) {
    float r; asm("v_exp_f32 %0, %1" : "=v"(r) : "v"(x)); return r;
}
__device__ __forceinline__ float log2g(float x) {
    float r; asm("v_log_f32 %0, %1" : "=v"(r) : "v"(x)); return r;
}
// Agent-scope store/load without cache-maintenance fences (sc1 path through
// the MALL coherence point; validated R9-R12: absmax 0).
__device__ __forceinline__ void st_agent(float* p, float v) {
    __hip_atomic_store(p, v, __ATOMIC_RELAXED, __HIP_MEMORY_SCOPE_AGENT);
}
__device__ __forceinline__ float ld_agent(const float* p) {
    return __hip_atomic_load(p, __ATOMIC_RELAXED, __HIP_MEMORY_SCOPE_AGENT);
}
// Whole-wave shift-up-by-1 via DPP WAVE_SHR1 (0x138): lane l gets src[l-1],
// lane 0 keeps `fill`. Pure VALU: no LDS round-trip, no lgkmcnt.
__device__ __forceinline__ float dpp_shr1(float x, float fill) {
    int r = __builtin_amdgcn_update_dpp(
        __builtin_bit_cast(int, fill), __builtin_bit_cast(int, x),
        0x138, 0xF, 0xF, false);
    return __builtin_bit_cast(float, r);
}
// One DPP row_shl<K> add step (ctrl must be a literal constant -> template).
template <int CTRL>
__device__ __forceinline__ float dpp_add(float x) {
    int s = __builtin_amdgcn_update_dpp(
        0, __builtin_bit_cast(int, x), CTRL, 0xF, 0xF, true);
    return x + __builtin_bit_cast(float, s);
}
// Wave sum to lane 0 (lanes 16/32/48 also hold it): DPP row_shl 1/2/4/8 on
// the VALU pipe + two cross-lane combines.
__device__ __forceinline__ float wave_sum_to0(float x) {
    x = dpp_add<0x101>(x);
    x = dpp_add<0x102>(x);
    x = dpp_add<0x104>(x);
    x = dpp_add<0x108>(x);
    x += __shfl_xor(x, 16, 64);
    x += __shfl_xor(x, 32, 64);
    return x;
}

// ---------------------------------------------------------------------------
// k0: per-tag counts -> 0.1*LOG2E/cnt (tiny, one block). Also zeroes kB's
// completion counter.
// ---------------------------------------------------------------------------
__global__ void k0_counts(const int* __restrict__ tag_ids,
                          float* __restrict__ invcnt2, int* __restrict__ counter) {
    __shared__ int c[NTAGS];
    if (threadIdx.x == 0) *counter = 0;
    if (threadIdx.x < NTAGS) c[threadIdx.x] = 0;
    __syncthreads();
    for (int v = threadIdx.x; v < VG_; v += 256)
        atomicAdd(&c[tag_ids[v]], 1);   // integer atomics: deterministic
    __syncthreads();
    if (threadIdx.x < NTAGS)
        invcnt2[threadIdx.x] = (0.1f * LOG2E) / (float)c[threadIdx.x];
}

// ---------------------------------------------------------------------------
// kA: booster + max-free base-2 logsumexp + gather lp at {blank, glosses}.
// Identical to R12. IDEMPOTENT: rewrites the same lp_ws values each launch —
// this round launches it 3x as an in-band timing probe (Δ/2 = warm kA cost).
// ---------------------------------------------------------------------------
__global__ __launch_bounds__(256) void kA_booster(
    const float* __restrict__ scores, const int* __restrict__ tag_ids,
    const int* __restrict__ glosses, const float* __restrict__ invcnt2,
    float* __restrict__ lp_ws)
{
    __shared__ float tm2L[4][NTAGS];   // wave-private rows; 128 B total
    const int tid  = threadIdx.x;
    const int lane = tid & 63;
    const int wv   = tid >> 6;
    const int row  = blockIdx.x * 4 + wv;      // [0, B*T)
    const int b    = row >> 8;                 // row / T_
    const float* srow = scores + (size_t)row * VG_;

    // Gather index (tiny load, issued early): lane 0 -> blank(0),
    // lanes 1..32 -> glosses[b, lane-1].
    const int gidx = (lane >= 1 && lane < 33) ? glosses[b * S_ + lane - 1] : 0;

    // Long-latency loads: scores (308 float4/row; 5/lane, last iter 52 lanes)
    // and tags (same shape, int4 from global, L2-resident).
    float4 sv[5];
    int4   tv[5];
#pragma unroll
    for (int i = 0; i < 5; ++i) {
        const int idx = i * 64 + lane;
        const bool act = (i < 4) || (lane < 52);
        sv[i] = act ? ((const float4*)srow)[idx]  : make_float4(0.f, 0.f, 0.f, 0.f);
        tv[i] = act ? ((const int4*)tag_ids)[idx] : make_int4(0, 0, 0, 0);
    }
    // Pre-issue gather loads (overlap pass-1 compute).
    const float gval = srow[gidx];
    const int   gtag = tag_ids[gidx];

    // Pass 1: per-tag sums (inactive elements contribute 0 to tag 0: harmless)
    float sums[NTAGS];
#pragma unroll
    for (int n = 0; n < NTAGS; ++n) sums[n] = 0.f;
#pragma unroll
    for (int i = 0; i < 5; ++i) {
        const float xs[4] = {sv[i].x, sv[i].y, sv[i].z, sv[i].w};
        const int   ts[4] = {tv[i].x, tv[i].y, tv[i].z, tv[i].w};
#pragma unroll
        for (int j = 0; j < 4; ++j) {
#pragma unroll
            for (int n = 0; n < NTAGS; ++n)
                sums[n] += (ts[j] == n) ? xs[j] : 0.f;
        }
    }
#pragma unroll
    for (int n = 0; n < NTAGS; ++n) sums[n] = wave_sum_to0(sums[n]);

    // Lane 0 publishes tm2 into the wave-private LDS row (no barrier).
    if (lane == 0) {
#pragma unroll
        for (int n = 0; n < NTAGS; ++n)
            tm2L[wv][n] = sums[n] * invcnt2[n];   // = 0.1*mean*LOG2E
    }
    __builtin_amdgcn_sched_barrier(0);  // pin ds_write before the ds_reads

    // Pass 2: se = sum exp2(x*LOG2E + tm2[tag])  (max-free)
    float se = 0.f;
#pragma unroll
    for (int i = 0; i < 5; ++i) {
        const float xs[4] = {sv[i].x, sv[i].y, sv[i].z, sv[i].w};
        const int   ts[4] = {tv[i].x, tv[i].y, tv[i].z, tv[i].w};
        const bool act = (i < 4) || (lane < 52);
#pragma unroll
        for (int j = 0; j < 4; ++j) {
            const float e = exp2g(fmaf(xs[j], LOG2E, tm2L[wv][ts[j]]));
            se += act ? e : 0.f;
        }
    }
    se = wave_sum_to0(se);
    const float se0 = __builtin_bit_cast(
        float, __builtin_amdgcn_readfirstlane(__builtin_bit_cast(int, se)));
    const float lse2 = log2g(se0);             // log2(sum e^x)

    // lp2 = x*LOG2E + tm2 - lse2. Store in log2 domain.
    if (lane < 33) {
        const float v = fmaf(gval, LOG2E, tm2L[wv][gtag]) - lse2;
        lp_ws[(size_t)row * LP_STRIDE + lane] = v;
    }
}

// ---------------------------------------------------------------------------
// kB scan body, specialized on whether every step commits (Tlen == T).
// ---------------------------------------------------------------------------
template <bool FULL>
__device__ __forceinline__ void scan_body(
    const float* __restrict__ tile, int lane, int off, bool ok2, int Tlen,
    float& alpha, float& a64)
{
    auto STEP = [&](int t, float lp, float lpB) {
        const float a1 = dpp_shr1(alpha, NEG_);          // lane0 -> NEG
        float a2 = dpp_shr1(a1, NEG_);                   // lanes0,1 -> NEG
        a2 = ok2 ? a2 : NEG_;
        const float m3 = fmaxf(alpha, fmaxf(a1, a2));    // v_max3
        const float e0 = exp2g(alpha - m3);
        const float e1 = exp2g(a1 - m3);
        const float e2 = exp2g(a2 - m3);
        const float nw = (m3 + lp) + log2g((e0 + e1) + e2);
        const float m2 = fmaxf(a64, alpha);              // a63 lane-local on 63
        const float n64 = (m2 + lpB) + log2g(exp2g(a64 - m2) + exp2g(alpha - m2));
        if (FULL || t < Tlen) { alpha = nw; a64 = n64; } // uniform
    };

    float cur[4], curB[4];
#pragma unroll
    for (int j = 0; j < 4; ++j) {
        cur[j]  = tile[(1 + j) * LP_STRIDE + off];
        curB[j] = tile[(1 + j) * LP_STRIDE];
    }
    int tbase = 1;
    for (int g = 0; g < 63; ++g) {
        float nxt[4], nxtB[4];
        const int tb2 = tbase + 4;             // last group reads pad row 256
#pragma unroll
        for (int j = 0; j < 4; ++j) {
            nxt[j]  = tile[(tb2 + j) * LP_STRIDE + off];
            nxtB[j] = tile[(tb2 + j) * LP_STRIDE];
        }
#pragma unroll
        for (int j = 0; j < 4; ++j) STEP(tbase + j, cur[j], curB[j]);
#pragma unroll
        for (int j = 0; j < 4; ++j) { cur[j] = nxt[j]; curB[j] = nxtB[j]; }
        tbase += 4;
    }
#pragma unroll
    for (int j = 0; j < 3; ++j) STEP(253 + j, cur[j], curB[j]);
}

// ---------------------------------------------------------------------------
// kB: blocks 0..63 = CTC alpha scan (lp tile staged to LDS, wave-0 scan).
// Block 64 = NLL gather. Fence-free completion (sc1 + vmcnt drain + RMW).
// ---------------------------------------------------------------------------
__global__ __launch_bounds__(256) void kB_ctc_nll_final(
    const float* __restrict__ lp_ws, const int* __restrict__ glosses,
    const int* __restrict__ frames_len, const int* __restrict__ glosses_len,
    const int* __restrict__ words, const float* __restrict__ words_out,
    float* __restrict__ loss_ws, float* __restrict__ nll_ws,
    int* __restrict__ counter, float* __restrict__ out)
{
    __shared__ __align__(16) float tile[(T_ + 1) * LP_STRIDE];  // +pad row
    __shared__ float red[256];
    const int tid = threadIdx.x;

    if (blockIdx.x == B_) {
        // ---- NLL gather: 4032 scattered reads, fixed-order tree reduce ----
        float acc = 0.f;
        for (int idx = tid; idx < B_ * (LW_ - 1); idx += 256) {
            const int b = idx / (LW_ - 1);
            const int t = idx - b * (LW_ - 1);
            const int tgt = words[b * LW_ + t + 1];
            if (tgt != 0)
                acc -= words_out[((size_t)b * LW_ + t) * VW_ + tgt];
        }
        red[tid] = acc;
        __syncthreads();
        for (int s = 128; s > 0; s >>= 1) {
            if (tid < s) red[tid] += red[tid + s];
            __syncthreads();
        }
        if (tid == 0) st_agent(nll_ws, red[0]);          // sc1
    } else {
        const int b = blockIdx.x;
        // ---- stage lp tile: 8704 floats = 2176 float4, 256 threads ----
        {
            const float4* src4 = (const float4*)(lp_ws + (size_t)b * T_ * LP_STRIDE);
            float4* dst4 = (float4*)tile;
            float4 r[9];
#pragma unroll
            for (int i = 0; i < 9; ++i) {
                const int idx = i * 256 + tid;
                if (idx < 2176) r[i] = src4[idx];
            }
#pragma unroll
            for (int i = 0; i < 9; ++i) {
                const int idx = i * 256 + tid;
                if (idx < 2176) dst4[idx] = r[i];
            }
        }
        __syncthreads();
        if (tid >= 64) return;                 // scan is single-wave
        const int lane = tid;

        // ext[l]: even -> blank, odd -> glosses[b, l>>1]
        const bool odd  = (lane & 1) != 0;
        const int  sIdx = (lane - 1) >> 1;     // valid when odd
        bool ok2 = false;                      // may take the l-2 skip path
        if (odd && sIdx >= 1) {
            const int g  = glosses[b * S_ + sIdx];
            const int gp = glosses[b * S_ + sIdx - 1];
            ok2 = (g != gp) && (g != 0);
        }
        const int off = odd ? (1 + sIdx) : 0;  // column in the 34-wide row

        float alpha = NEG_;
        float a64   = NEG_;                    // state 64; valid on lane 63
        {
            const float lp00 = tile[off];
            if (lane <= 1) alpha = lp00;       // alpha0[0], alpha0[1]
        }
        const int Tlen = frames_len[b];

        if (Tlen == T_) scan_body<true >(tile, lane, off, ok2, Tlen, alpha, a64);
        else            scan_body<false>(tile, lane, off, ok2, Tlen, alpha, a64);

        const float a64v = __shfl(a64, 63, 64);
        const int i1 = 2 * glosses_len[b];     // in [2, 64]
        const int i0 = i1 - 1;
        const float A0 = __shfl(alpha, i0, 64);
        const float A1 = (i1 >= 64) ? a64v : __shfl(alpha, i1, 64);
        const float mm = fmaxf(A0, A1);
        float loss = -(mm + log2g(exp2g(A0 - mm) + exp2g(A1 - mm))) * LN2;
        if (loss > 1e29f) loss = 0.f;
        if (lane == 0) st_agent(&loss_ws[b], loss);      // sc1
    }

    // ---- completion, fence-free: drain own sc1 store, one RMW each ----
    asm volatile("s_waitcnt vmcnt(0)" ::: "memory");
    int old = 0;
    if (tid == 0) old = atomicAdd(counter, 1);
    if (tid < 64) {
        old = __shfl(old, 0, 64);
        if (old == B_) {                       // 65th arrival
            float v = ld_agent(&loss_ws[tid]); // sc1: MALL-coherent
#pragma unroll
            for (int o = 32; o >= 1; o >>= 1) v += __shfl_xor(v, o, 64);
            if (tid == 0) {
                const float trans = ld_agent(nll_ws);
                out[0] = v + trans;            // GLOSS_W = WORD_W = 1
                out[1] = v;
                out[2] = trans;
            }
        }
    }
}

// ---------------------------------------------------------------------------
// MEASUREMENT ROUND: kA launched 3x (idempotent). Delta vs R12 isolates
// kA's warm cost: kA_warm ~= (dur - 52.4 - 2us) / 2.
// ---------------------------------------------------------------------------
extern "C" void kernel_launch(void* const* d_in, const int* in_sizes, int n_in,
                              void* d_out, int out_size, void* d_ws, size_t ws_size,
                              hipStream_t stream) {
    const int*   glosses     = (const int*)d_in[0];
    const int*   words       = (const int*)d_in[1];
    const float* scores      = (const float*)d_in[2];
    const float* words_out   = (const float*)d_in[3];
    const int*   frames_len  = (const int*)d_in[4];
    const int*   glosses_len = (const int*)d_in[5];
    const int*   tag_ids     = (const int*)d_in[6];
    float* out = (float*)d_out;

    float* w       = (float*)d_ws;
    int*   counter = (int*)d_ws;   // w[0]
    float* invcnt2 = w + 8;        // 8 floats: 0.1*LOG2E/cnt[n]
    float* loss_ws = w + 16;       // 64
    float* nll_ws  = w + 80;       // 1
    float* lp_ws   = w + 128;      // B*T*34 floats = 2.23 MB (16B-aligned)

    k0_counts<<<1, 256, 0, stream>>>(tag_ids, invcnt2, counter);
    kA_booster<<<(B_ * T_) / 4, 256, 0, stream>>>(scores, tag_ids, glosses,
                                                  invcnt2, lp_ws);
    kA_booster<<<(B_ * T_) / 4, 256, 0, stream>>>(scores, tag_ids, glosses,
                                                  invcnt2, lp_ws);
    kA_booster<<<(B_ * T_) / 4, 256, 0, stream>>>(scores, tag_ids, glosses,
                                                  invcnt2, lp_ws);
    kB_ctc_nll_final<<<B_ + 1, 256, 0, stream>>>(lp_ws, glosses, frames_len,
                                                 glosses_len, words, words_out,
                                                 loss_ws, nll_ws, counter, out);
}

// Round 14
// 52.185 us; speedup vs baseline: 1.6831x; 1.6831x over previous
//
#include <hip/hip_runtime.h>

// Problem constants (from reference)
#define B_    64
#define T_    256
#define VG_   1232
#define S_    32
#define LW_   64
#define VW_   8000
#define NTAGS 8
#define NEG_  (-1e30f)
#define LP_STRIDE 34   // per (b,t): [0]=blank lp, [1..32]=gloss lp, [33]=pad
#define LOG2E 1.44269504088896340736f
#define LN2   0.69314718055994530942f

__device__ __forceinline__ float exp2g(float x) {
    float r; asm("v_exp_f32 %0, %1" : "=v"(r) : "v"(x)); return r;
}
__device__ __forceinline__ float log2g(float x) {
    float r; asm("v_log_f32 %0, %1" : "=v"(r) : "v"(x)); return r;
}
// Agent-scope store/load without cache-maintenance fences (sc1 path through
// the MALL coherence point; validated R9-R13: absmax 0).
__device__ __forceinline__ void st_agent(float* p, float v) {
    __hip_atomic_store(p, v, __ATOMIC_RELAXED, __HIP_MEMORY_SCOPE_AGENT);
}
__device__ __forceinline__ float ld_agent(const float* p) {
    return __hip_atomic_load(p, __ATOMIC_RELAXED, __HIP_MEMORY_SCOPE_AGENT);
}
// Whole-wave shift-up-by-1 via DPP WAVE_SHR1 (0x138): lane l gets src[l-1],
// lane 0 keeps `fill`. Pure VALU: no LDS round-trip, no lgkmcnt.
__device__ __forceinline__ float dpp_shr1(float x, float fill) {
    int r = __builtin_amdgcn_update_dpp(
        __builtin_bit_cast(int, fill), __builtin_bit_cast(int, x),
        0x138, 0xF, 0xF, false);
    return __builtin_bit_cast(float, r);
}
// One DPP row_shl<K> add step (ctrl must be a literal constant -> template).
template <int CTRL>
__device__ __forceinline__ float dpp_add(float x) {
    int s = __builtin_amdgcn_update_dpp(
        0, __builtin_bit_cast(int, x), CTRL, 0xF, 0xF, true);
    return x + __builtin_bit_cast(float, s);
}
// Wave sum to lane 0 (lanes 16/32/48 also hold it): DPP row_shl 1/2/4/8 on
// the VALU pipe + two cross-lane combines.
__device__ __forceinline__ float wave_sum_to0(float x) {
    x = dpp_add<0x101>(x);
    x = dpp_add<0x102>(x);
    x = dpp_add<0x104>(x);
    x = dpp_add<0x108>(x);
    x += __shfl_xor(x, 16, 64);
    x += __shfl_xor(x, 32, 64);
    return x;
}

// ---------------------------------------------------------------------------
// k0: per-tag counts -> 0.1*LOG2E/cnt (tiny, one block). Also zeroes kB's
// completion counter.
// ---------------------------------------------------------------------------
__global__ void k0_counts(const int* __restrict__ tag_ids,
                          float* __restrict__ invcnt2, int* __restrict__ counter) {
    __shared__ int c[NTAGS];
    if (threadIdx.x == 0) *counter = 0;
    if (threadIdx.x < NTAGS) c[threadIdx.x] = 0;
    __syncthreads();
    for (int v = threadIdx.x; v < VG_; v += 256)
        atomicAdd(&c[tag_ids[v]], 1);   // integer atomics: deterministic
    __syncthreads();
    if (threadIdx.x < NTAGS)
        invcnt2[threadIdx.x] = (0.1f * LOG2E) / (float)c[threadIdx.x];
}

// ---------------------------------------------------------------------------
// kA: booster + max-free base-2 logsumexp + gather lp at {blank, glosses}.
// Barrier-free; ~15-17 us warm (measured R13), near its 13 us HBM floor.
// Unchanged from R12.
// ---------------------------------------------------------------------------
__global__ __launch_bounds__(256) void kA_booster(
    const float* __restrict__ scores, const int* __restrict__ tag_ids,
    const int* __restrict__ glosses, const float* __restrict__ invcnt2,
    float* __restrict__ lp_ws)
{
    __shared__ float tm2L[4][NTAGS];   // wave-private rows; 128 B total
    const int tid  = threadIdx.x;
    const int lane = tid & 63;
    const int wv   = tid >> 6;
    const int row  = blockIdx.x * 4 + wv;      // [0, B*T)
    const int b    = row >> 8;                 // row / T_
    const float* srow = scores + (size_t)row * VG_;

    // Gather index (tiny load, issued early): lane 0 -> blank(0),
    // lanes 1..32 -> glosses[b, lane-1].
    const int gidx = (lane >= 1 && lane < 33) ? glosses[b * S_ + lane - 1] : 0;

    // Long-latency loads: scores (308 float4/row; 5/lane, last iter 52 lanes)
    // and tags (same shape, int4 from global, L2-resident).
    float4 sv[5];
    int4   tv[5];
#pragma unroll
    for (int i = 0; i < 5; ++i) {
        const int idx = i * 64 + lane;
        const bool act = (i < 4) || (lane < 52);
        sv[i] = act ? ((const float4*)srow)[idx]  : make_float4(0.f, 0.f, 0.f, 0.f);
        tv[i] = act ? ((const int4*)tag_ids)[idx] : make_int4(0, 0, 0, 0);
    }
    // Pre-issue gather loads (overlap pass-1 compute).
    const float gval = srow[gidx];
    const int   gtag = tag_ids[gidx];

    // Pass 1: per-tag sums (inactive elements contribute 0 to tag 0: harmless)
    float sums[NTAGS];
#pragma unroll
    for (int n = 0; n < NTAGS; ++n) sums[n] = 0.f;
#pragma unroll
    for (int i = 0; i < 5; ++i) {
        const float xs[4] = {sv[i].x, sv[i].y, sv[i].z, sv[i].w};
        const int   ts[4] = {tv[i].x, tv[i].y, tv[i].z, tv[i].w};
#pragma unroll
        for (int j = 0; j < 4; ++j) {
#pragma unroll
            for (int n = 0; n < NTAGS; ++n)
                sums[n] += (ts[j] == n) ? xs[j] : 0.f;
        }
    }
#pragma unroll
    for (int n = 0; n < NTAGS; ++n) sums[n] = wave_sum_to0(sums[n]);

    // Lane 0 publishes tm2 into the wave-private LDS row (no barrier).
    if (lane == 0) {
#pragma unroll
        for (int n = 0; n < NTAGS; ++n)
            tm2L[wv][n] = sums[n] * invcnt2[n];   // = 0.1*mean*LOG2E
    }
    __builtin_amdgcn_sched_barrier(0);  // pin ds_write before the ds_reads

    // Pass 2: se = sum exp2(x*LOG2E + tm2[tag])  (max-free)
    float se = 0.f;
#pragma unroll
    for (int i = 0; i < 5; ++i) {
        const float xs[4] = {sv[i].x, sv[i].y, sv[i].z, sv[i].w};
        const int   ts[4] = {tv[i].x, tv[i].y, tv[i].z, tv[i].w};
        const bool act = (i < 4) || (lane < 52);
#pragma unroll
        for (int j = 0; j < 4; ++j) {
            const float e = exp2g(fmaf(xs[j], LOG2E, tm2L[wv][ts[j]]));
            se += act ? e : 0.f;
        }
    }
    se = wave_sum_to0(se);
    const float se0 = __builtin_bit_cast(
        float, __builtin_amdgcn_readfirstlane(__builtin_bit_cast(int, se)));
    const float lse2 = log2g(se0);             // log2(sum e^x)

    // lp2 = x*LOG2E + tm2 - lse2. Store in log2 domain.
    if (lane < 33) {
        const float v = fmaf(gval, LOG2E, tm2L[wv][gtag]) - lse2;
        lp_ws[(size_t)row * LP_STRIDE + lane] = v;
    }
}

// ---------------------------------------------------------------------------
// kB scan body, specialized on whether every step commits (Tlen == T).
// ---------------------------------------------------------------------------
template <bool FULL>
__device__ __forceinline__ void scan_body(
    const float* __restrict__ tile, int lane, int off, bool ok2, int Tlen,
    float& alpha, float& a64)
{
    auto STEP = [&](int t, float lp, float lpB) {
        const float a1 = dpp_shr1(alpha, NEG_);          // lane0 -> NEG
        float a2 = dpp_shr1(a1, NEG_);                   // lanes0,1 -> NEG
        a2 = ok2 ? a2 : NEG_;
        const float m3 = fmaxf(alpha, fmaxf(a1, a2));    // v_max3
        const float e0 = exp2g(alpha - m3);
        const float e1 = exp2g(a1 - m3);
        const float e2 = exp2g(a2 - m3);
        const float nw = (m3 + lp) + log2g((e0 + e1) + e2);
        const float m2 = fmaxf(a64, alpha);              // a63 lane-local on 63
        const float n64 = (m2 + lpB) + log2g(exp2g(a64 - m2) + exp2g(alpha - m2));
        if (FULL || t < Tlen) { alpha = nw; a64 = n64; } // uniform
    };

    float cur[4], curB[4];
#pragma unroll
    for (int j = 0; j < 4; ++j) {
        cur[j]  = tile[(1 + j) * LP_STRIDE + off];
        curB[j] = tile[(1 + j) * LP_STRIDE];
    }
    int tbase = 1;
    for (int g = 0; g < 63; ++g) {
        float nxt[4], nxtB[4];
        const int tb2 = tbase + 4;             // last group reads pad row 256
#pragma unroll
        for (int j = 0; j < 4; ++j) {
            nxt[j]  = tile[(tb2 + j) * LP_STRIDE + off];
            nxtB[j] = tile[(tb2 + j) * LP_STRIDE];
        }
#pragma unroll
        for (int j = 0; j < 4; ++j) STEP(tbase + j, cur[j], curB[j]);
#pragma unroll
        for (int j = 0; j < 4; ++j) { cur[j] = nxt[j]; curB[j] = nxtB[j]; }
        tbase += 4;
    }
#pragma unroll
    for (int j = 0; j < 3; ++j) STEP(253 + j, cur[j], curB[j]);
}

// ---------------------------------------------------------------------------
// kB: 64 blocks, one per batch. Each block:
//   1. issues its OWN 63 NLL gathers first (lanes 0..62, latency hides under
//      staging+scan) — the single-block 4032-gather convoy is gone;
//   2. stages its 256x34 lp tile to LDS, wave-0 scans;
//   3. wave-reduces the NLL partial, stores loss_ws[b] + nll_ws[b] (sc1);
//   4. fence-free completion (vmcnt drain + RMW); 64th arrival reduces both.
// ---------------------------------------------------------------------------
__global__ __launch_bounds__(256) void kB_ctc_nll_final(
    const float* __restrict__ lp_ws, const int* __restrict__ glosses,
    const int* __restrict__ frames_len, const int* __restrict__ glosses_len,
    const int* __restrict__ words, const float* __restrict__ words_out,
    float* __restrict__ loss_ws, float* __restrict__ nll_ws,
    int* __restrict__ counter, float* __restrict__ out)
{
    __shared__ __align__(16) float tile[(T_ + 1) * LP_STRIDE];  // +pad row
    const int tid = threadIdx.x;
    const int b   = blockIdx.x;

    // ---- NLL gather for this batch (issued FIRST: 2-deep dependent load
    //      chain rides concurrently with the staging loads below) ----
    float nacc = 0.f;
    if (tid < LW_ - 1) {
        const int tgt = words[b * LW_ + tid + 1];
        if (tgt != 0)
            nacc = -words_out[((size_t)b * LW_ + tid) * VW_ + tgt];
    }

    // ---- stage lp tile: 8704 floats = 2176 float4, 256 threads ----
    {
        const float4* src4 = (const float4*)(lp_ws + (size_t)b * T_ * LP_STRIDE);
        float4* dst4 = (float4*)tile;
        float4 r[9];
#pragma unroll
        for (int i = 0; i < 9; ++i) {
            const int idx = i * 256 + tid;
            if (idx < 2176) r[i] = src4[idx];
        }
#pragma unroll
        for (int i = 0; i < 9; ++i) {
            const int idx = i * 256 + tid;
            if (idx < 2176) dst4[idx] = r[i];
        }
    }
    __syncthreads();
    if (tid >= 64) return;                 // scan is single-wave
    const int lane = tid;

    // ext[l]: even -> blank, odd -> glosses[b, l>>1]
    const bool odd  = (lane & 1) != 0;
    const int  sIdx = (lane - 1) >> 1;     // valid when odd
    bool ok2 = false;                      // may take the l-2 skip path
    if (odd && sIdx >= 1) {
        const int g  = glosses[b * S_ + sIdx];
        const int gp = glosses[b * S_ + sIdx - 1];
        ok2 = (g != gp) && (g != 0);
    }
    const int off = odd ? (1 + sIdx) : 0;  // column in the 34-wide row

    float alpha = NEG_;
    float a64   = NEG_;                    // state 64; valid on lane 63
    {
        const float lp00 = tile[off];
        if (lane <= 1) alpha = lp00;       // alpha0[0], alpha0[1]
    }
    const int Tlen = frames_len[b];

    if (Tlen == T_) scan_body<true >(tile, lane, off, ok2, Tlen, alpha, a64);
    else            scan_body<false>(tile, lane, off, ok2, Tlen, alpha, a64);

    const float a64v = __shfl(a64, 63, 64);
    const int i1 = 2 * glosses_len[b];     // in [2, 64]
    const int i0 = i1 - 1;
    const float A0 = __shfl(alpha, i0, 64);
    const float A1 = (i1 >= 64) ? a64v : __shfl(alpha, i1, 64);
    const float mm = fmaxf(A0, A1);
    float loss = -(mm + log2g(exp2g(A0 - mm) + exp2g(A1 - mm))) * LN2;
    if (loss > 1e29f) loss = 0.f;

    // NLL partial: lanes 0..62 hold gathers (lane 63 = 0); fixed-order sum.
    nacc = wave_sum_to0(nacc);
    if (lane == 0) {
        st_agent(&loss_ws[b], loss);       // sc1
        st_agent(&nll_ws[b], nacc);        // sc1
    }

    // ---- completion, fence-free: drain own sc1 stores, one RMW ----
    asm volatile("s_waitcnt vmcnt(0)" ::: "memory");
    int old = 0;
    if (lane == 0) old = atomicAdd(counter, 1);
    old = __shfl(old, 0, 64);
    if (old == B_ - 1) {                   // 64th arrival
        float v = ld_agent(&loss_ws[lane]); // sc1: MALL-coherent
        float u = ld_agent(&nll_ws[lane]);
#pragma unroll
        for (int o = 32; o >= 1; o >>= 1) {
            v += __shfl_xor(v, o, 64);
            u += __shfl_xor(u, o, 64);
        }
        if (lane == 0) {
            out[0] = v + u;                // GLOSS_W = WORD_W = 1
            out[1] = v;
            out[2] = u;
        }
    }
}

// ---------------------------------------------------------------------------
extern "C" void kernel_launch(void* const* d_in, const int* in_sizes, int n_in,
                              void* d_out, int out_size, void* d_ws, size_t ws_size,
                              hipStream_t stream) {
    const int*   glosses     = (const int*)d_in[0];
    const int*   words       = (const int*)d_in[1];
    const float* scores      = (const float*)d_in[2];
    const float* words_out   = (const float*)d_in[3];
    const int*   frames_len  = (const int*)d_in[4];
    const int*   glosses_len = (const int*)d_in[5];
    const int*   tag_ids     = (const int*)d_in[6];
    float* out = (float*)d_out;

    float* w       = (float*)d_ws;
    int*   counter = (int*)d_ws;   // w[0]
    float* invcnt2 = w + 8;        // 8 floats: 0.1*LOG2E/cnt[n]
    float* loss_ws = w + 16;       // 64
    float* nll_ws  = w + 96;       // 64 (per-batch NLL partials)
    float* lp_ws   = w + 192;      // B*T*34 floats = 2.23 MB (16B-aligned)

    k0_counts<<<1, 256, 0, stream>>>(tag_ids, invcnt2, counter);
    kA_booster<<<(B_ * T_) / 4, 256, 0, stream>>>(scores, tag_ids, glosses,
                                                  invcnt2, lp_ws);
    kB_ctc_nll_final<<<B_, 256, 0, stream>>>(lp_ws, glosses, frames_len,
                                             glosses_len, words, words_out,
                                             loss_ws, nll_ws, counter, out);
}